// Round 2
// baseline (1380.824 us; speedup 1.0000x reference)
//
#include <hip/hip_runtime.h>

static __device__ __forceinline__ float gelu(float x) {
    return 0.5f * x * (1.0f + erff(x * 0.70710678118654752f));
}

// ---------------- encoder: h = gelu(cat(x,grid)@W1+b1)@W2+b2 ----------------
__global__ void k_encode(const float* __restrict__ x,
                         const float* __restrict__ grid,
                         const float* __restrict__ W1,
                         const float* __restrict__ b1,
                         const float* __restrict__ W2,
                         const float* __restrict__ b2,
                         float* __restrict__ h, int N)
{
    int n = blockIdx.x * blockDim.x + threadIdx.x;
    if (n >= N) return;
    float in[12];
#pragma unroll
    for (int k = 0; k < 10; k++) in[k] = x[n * 10 + k];
    in[10] = grid[n * 2 + 0];
    in[11] = grid[n * 2 + 1];
    float out[64];
#pragma unroll
    for (int o = 0; o < 64; o++) out[o] = b2[o];
    for (int jc = 0; jc < 4; jc++) {           // 128 mids in 4 chunks of 32
        float macc[32];
#pragma unroll
        for (int i = 0; i < 32; i++) macc[i] = b1[jc * 32 + i];
#pragma unroll
        for (int k = 0; k < 12; k++) {
            float xv = in[k];
            const float* w1r = W1 + k * 128 + jc * 32;   // wave-uniform -> s_load
#pragma unroll
            for (int i = 0; i < 32; i++) macc[i] += xv * w1r[i];
        }
#pragma unroll
        for (int i = 0; i < 32; i++) {
            float m = gelu(macc[i]);
            const float* w2r = W2 + (jc * 32 + i) * 64;  // wave-uniform row
#pragma unroll
            for (int o = 0; o < 64; o++) out[o] += m * w2r[o];
        }
    }
    float4* hp = (float4*)(h + (size_t)n * 64);
#pragma unroll
    for (int q = 0; q < 16; q++)
        hp[q] = make_float4(out[4 * q], out[4 * q + 1], out[4 * q + 2], out[4 * q + 3]);
}

// ---------------- degree count ----------------
__global__ void k_count(const int* __restrict__ ei, int* __restrict__ cnt, int E)
{
    int e = blockIdx.x * blockDim.x + threadIdx.x;
    if (e < E) atomicAdd(&cnt[ei[E + e]], 1);
}

// ---------------- single-block exclusive scan of degrees -> off, woff ----------------
__global__ void k_scan(const int* __restrict__ cnt, int* __restrict__ off,
                       int* __restrict__ woff, int N)
{
    __shared__ int part[1024];
    int t = threadIdx.x;
    int per = (N + 1023) >> 10;
    int base = t * per;
    int s = 0;
    for (int i = 0; i < per; i++) { int idx = base + i; if (idx < N) s += cnt[idx]; }
    part[t] = s;
    __syncthreads();
    for (int d = 1; d < 1024; d <<= 1) {
        int v = (t >= d) ? part[t - d] : 0;
        __syncthreads();
        part[t] += v;
        __syncthreads();
    }
    int run = part[t] - s;   // exclusive prefix for this thread's chunk
    for (int i = 0; i < per; i++) {
        int idx = base + i;
        if (idx < N) { off[idx] = run; woff[idx] = run; run += cnt[idx]; }
    }
}

// ---------------- scatter src indices into CSR-by-dst order ----------------
__global__ void k_scatter(const int* __restrict__ ei, int* __restrict__ woff,
                          int* __restrict__ ssrc, int E)
{
    int e = blockIdx.x * blockDim.x + threadIdx.x;
    if (e < E) {
        int src = ei[e];
        int dst = ei[E + e];
        int p = atomicAdd(&woff[dst], 1);
        ssrc[p] = src;
    }
}

// ---------------- gather per-node sums: sum_h[64], sum_g[2], sum_dist ----------------
// 16 lanes per node; each lane owns 4 h-dims (float4): 256B coalesced per edge.
__global__ void k_gather(const float* __restrict__ h,
                         const float* __restrict__ grid,
                         const int* __restrict__ ssrc, const int* __restrict__ off,
                         const int* __restrict__ cnt,
                         float* __restrict__ sum_h, float* __restrict__ sum_g,
                         float* __restrict__ sum_d, int N)
{
    int tid = blockIdx.x * blockDim.x + threadIdx.x;
    int n = tid >> 4;
    int l = tid & 15;
    if (n >= N) return;
    int beg = off[n];
    int dg = cnt[n];
    const float4* h4 = (const float4*)h;
    float4 a = make_float4(0.f, 0.f, 0.f, 0.f);
    float sgx = 0.f, sgy = 0.f, sd = 0.f, gix = 0.f, giy = 0.f;
    if (l == 0) { gix = grid[2 * n]; giy = grid[2 * n + 1]; }
    for (int i = 0; i < dg; i++) {
        int s = ssrc[beg + i];
        float4 v = h4[(size_t)s * 16 + l];
        a.x += v.x; a.y += v.y; a.z += v.z; a.w += v.w;
        if (l == 0) {
            float gx = grid[2 * s], gy = grid[2 * s + 1];
            float dx = gix - gx, dy = giy - gy;
            sd += sqrtf(dx * dx + dy * dy);
            sgx += gx; sgy += gy;
        }
    }
    ((float4*)sum_h)[(size_t)n * 16 + l] = a;
    if (l == 0) { sum_d[n] = sd; sum_g[2 * n] = sgx; sum_g[2 * n + 1] = sgy; }
}

// ---------------- node update + decoder, fused ----------------
// aggr folded: acc = bw + deg*bk + sd*Wk0 + deg*gi@Wk[1:3] + sg@Wk[3:5]
//                   + h@Ww + deg*(h@WkC) + sum_h@WkD ; h2=gelu(acc); decode.
__global__ void k_node(const float* __restrict__ h, const float* __restrict__ sum_h,
                       const float* __restrict__ sum_g, const float* __restrict__ sum_d,
                       const int* __restrict__ cnt, const float* __restrict__ grid,
                       const float* __restrict__ Wk, const float* __restrict__ bk,
                       const float* __restrict__ Ww, const float* __restrict__ bw,
                       const float* __restrict__ Wd1, const float* __restrict__ bd1,
                       const float* __restrict__ Wd2, const float* __restrict__ bd2,
                       float* __restrict__ out, int N)
{
    int n = blockIdx.x * blockDim.x + threadIdx.x;
    if (n >= N) return;
    float deg = (float)cnt[n];
    float sd = sum_d[n];
    float sgx = sum_g[2 * n], sgy = sum_g[2 * n + 1];
    float gix = grid[2 * n] * deg, giy = grid[2 * n + 1] * deg;

    float acc[64];
#pragma unroll
    for (int o = 0; o < 64; o++) {
        acc[o] = bw[o] + deg * bk[o] + sd * Wk[o]
               + gix * Wk[64 + o] + giy * Wk[128 + o]
               + sgx * Wk[192 + o] + sgy * Wk[256 + o];
    }
    const float4* hp = (const float4*)(h + (size_t)n * 64);
    const float4* sp = (const float4*)(sum_h + (size_t)n * 64);
    for (int kc = 0; kc < 16; kc++) {
        float4 hv = hp[kc];
        float4 sv = sp[kc];
        float hk[4] = { hv.x, hv.y, hv.z, hv.w };
        float sk[4] = { sv.x, sv.y, sv.z, sv.w };
#pragma unroll
        for (int q = 0; q < 4; q++) {
            int k = kc * 4 + q;
            float hkv = hk[q];
            float hdv = deg * hkv;
            float skv = sk[q];
            const float* ww  = Ww + k * 64;             // wave-uniform rows
            const float* wkc = Wk + (5 + k) * 64;
            const float* wkd = Wk + (69 + k) * 64;
#pragma unroll
            for (int o = 0; o < 64; o++)
                acc[o] += hkv * ww[o] + hdv * wkc[o] + skv * wkd[o];
        }
    }
#pragma unroll
    for (int o = 0; o < 64; o++) acc[o] = gelu(acc[o]);   // acc now holds h2

    float outa = bd2[0];
    for (int mc = 0; mc < 4; mc++) {                       // 128 mids, chunks of 32
        float macc[32];
#pragma unroll
        for (int i = 0; i < 32; i++) macc[i] = bd1[mc * 32 + i];
#pragma unroll
        for (int o = 0; o < 64; o++) {
            float hv = acc[o];
            const float* w = Wd1 + o * 128 + mc * 32;      // wave-uniform
#pragma unroll
            for (int i = 0; i < 32; i++) macc[i] += hv * w[i];
        }
#pragma unroll
        for (int i = 0; i < 32; i++) outa += gelu(macc[i]) * Wd2[mc * 32 + i];
    }
    out[n] = outa;
}

extern "C" void kernel_launch(void* const* d_in, const int* in_sizes, int n_in,
                              void* d_out, int out_size, void* d_ws, size_t ws_size,
                              hipStream_t stream)
{
    const float* x    = (const float*)d_in[0];
    const float* grid = (const float*)d_in[1];
    const int*   ei   = (const int*)d_in[2];
    const float* W1   = (const float*)d_in[3];
    const float* b1   = (const float*)d_in[4];
    const float* W2   = (const float*)d_in[5];
    const float* b2   = (const float*)d_in[6];
    const float* Wk   = (const float*)d_in[7];
    const float* bk   = (const float*)d_in[8];
    const float* Ww   = (const float*)d_in[9];
    const float* bw   = (const float*)d_in[10];
    const float* Wd1  = (const float*)d_in[11];
    const float* bd1  = (const float*)d_in[12];
    const float* Wd2  = (const float*)d_in[13];
    const float* bd2  = (const float*)d_in[14];
    float* out = (float*)d_out;

    int N = in_sizes[0] / 10;
    int E = in_sizes[2] / 2;

    char* ws = (char*)d_ws;
    size_t o_h    = 0;
    size_t o_sumh = o_h    + (size_t)N * 64 * 4;
    size_t o_sumg = o_sumh + (size_t)N * 64 * 4;
    size_t o_sumd = o_sumg + (size_t)N * 2 * 4;
    size_t o_cnt  = o_sumd + (size_t)N * 4;
    size_t o_off  = o_cnt  + (size_t)N * 4;
    size_t o_woff = o_off  + (size_t)N * 4;
    size_t o_ssrc = o_woff + (size_t)N * 4;

    float* h     = (float*)(ws + o_h);
    float* sum_h = (float*)(ws + o_sumh);
    float* sum_g = (float*)(ws + o_sumg);
    float* sum_d = (float*)(ws + o_sumd);
    int*   cnt   = (int*)  (ws + o_cnt);
    int*   off   = (int*)  (ws + o_off);
    int*   woff  = (int*)  (ws + o_woff);
    int*   ssrc  = (int*)  (ws + o_ssrc);

    hipMemsetAsync(cnt, 0, (size_t)N * 4, stream);

    k_encode<<<dim3((N + 255) / 256), dim3(256), 0, stream>>>(x, grid, W1, b1, W2, b2, h, N);
    k_count<<<dim3((E + 255) / 256), dim3(256), 0, stream>>>(ei, cnt, E);
    k_scan<<<dim3(1), dim3(1024), 0, stream>>>(cnt, off, woff, N);
    k_scatter<<<dim3((E + 255) / 256), dim3(256), 0, stream>>>(ei, woff, ssrc, E);
    k_gather<<<dim3((N * 16 + 255) / 256), dim3(256), 0, stream>>>(h, grid, ssrc, off, cnt,
                                                                    sum_h, sum_g, sum_d, N);
    k_node<<<dim3((N + 255) / 256), dim3(256), 0, stream>>>(h, sum_h, sum_g, sum_d, cnt, grid,
                                                            Wk, bk, Ww, bw, Wd1, bd1, Wd2, bd2,
                                                            out, N);
}